// Round 6
// baseline (253.263 us; speedup 1.0000x reference)
//
#include <hip/hip_runtime.h>
#include <hip/hip_fp16.h>
#include <math.h>

// ---------------------------------------------------------------------------
// GCN: 3x (GCNConv -> BatchNorm -> ReLU) -> fc1+ReLU -> fc2 -> log_softmax
// N=100000, E=1600000, IN=128, HID=64, classes=2.
// Conv biases cancel through BN mean-subtraction -> skipped.
// GEMMs: v_mfma_f32_16x16x32_f16 (fp16 in, fp32 accum).
// CSR per call: LDS bucket-sort partition (coalesced rec writes) -> per-bucket
// hist+scan+scatter (recomputes bucket prefix locally; writes dis/row_ptr/ssrc).
// Hp/AGG intermediates fp16; BN-apply+ReLU fused into next consumer.
// No hipMemsetAsync in the graph: k_zero kernel clears gcur+stats (~2us vs
// ~39us fill dispatch observed in R5 profile).
// ---------------------------------------------------------------------------

#define BUCK_CAP 6144   // slots per 256-node bucket (mean 4096, +32 sigma)
#define PB_EDGES 8192   // edges per k_part block

typedef _Float16 f16x8 __attribute__((ext_vector_type(8)));
typedef float f32x4 __attribute__((ext_vector_type(4)));

union H4U { uint2 u; __half h[4]; };
union H8U { uint4 u; __half h[8]; };

__device__ inline uint2 pack4(float a, float b, float c, float d) {
    H4U t;
    t.h[0] = __float2half_rn(a); t.h[1] = __float2half_rn(b);
    t.h[2] = __float2half_rn(c); t.h[3] = __float2half_rn(d);
    return t.u;
}
__device__ inline float4 unpack4(uint2 u) {
    H4U t; t.u = u;
    return make_float4(__half2float(t.h[0]), __half2float(t.h[1]),
                       __half2float(t.h[2]), __half2float(t.h[3]));
}
__device__ inline void upadd8(uint4 u, float* a) {
    H8U t; t.u = u;
#pragma unroll
    for (int i = 0; i < 8; ++i) a[i] += __half2float(t.h[i]);
}

// Zero gcur (512 ints) + stats (384 floats). Replaces hipMemsetAsync fill node.
__global__ __launch_bounds__(256) void k_zero(int* __restrict__ gcur,
                                              float* __restrict__ stats) {
    int t = threadIdx.x;
    gcur[t] = 0; gcur[t + 256] = 0;
    stats[t] = 0.f;
    if (t < 128) stats[256 + t] = 0.f;
}

// Pass A: LDS bucket-sort partition. Block reads 8192 edges, histograms by
// bucket (dst>>8), reserves global space (1 atomic per active bucket),
// LDS-scan -> LDS-scatter (bucket-ordered), coalesced flush.
// Record = (src<<8)|(dst&255).
__global__ __launch_bounds__(256) void k_part(const int* __restrict__ src,
                                              const int* __restrict__ dst,
                                              int* __restrict__ gcur,
                                              unsigned* __restrict__ rec,
                                              int E, int NB) {
    __shared__ int hist[512];                 // counts -> cursors
    __shared__ int lbase[512];                // local exclusive prefix
    __shared__ int gbase[512];                // reserved global base
    __shared__ int stmp[256];
    __shared__ unsigned stage[PB_EDGES];      // 32 KB
    __shared__ unsigned short sbkt[PB_EDGES]; // 16 KB
    const int tid = threadIdx.x;
    const int e0 = blockIdx.x * PB_EDGES;
    const int e1 = min(e0 + PB_EDGES, E);
    const int cnt = e1 - e0;

    hist[tid] = 0; hist[tid + 256] = 0;
    __syncthreads();
    for (int i = e0 + tid; i < e1; i += 256)
        atomicAdd(&hist[dst[i] >> 8], 1);
    __syncthreads();
    // reserve global space per active bucket
    for (int b = tid; b < NB; b += 256) {
        int c = hist[b];
        gbase[b] = c ? atomicAdd(&gcur[b], c) : 0;
    }
    // exclusive scan of hist[0..511]; thread t owns entries 2t, 2t+1
    int h0 = hist[2 * tid], h1 = hist[2 * tid + 1];
    int psum = h0 + h1;
    stmp[tid] = psum;
    __syncthreads();
    int x = psum;
    for (int off = 1; off < 256; off <<= 1) {
        int y = (tid >= off) ? stmp[tid - off] : 0;
        __syncthreads();
        x += y;
        stmp[tid] = x;
        __syncthreads();
    }
    int excl = x - psum;
    lbase[2 * tid] = excl;
    lbase[2 * tid + 1] = excl + h0;
    __syncthreads();
    hist[2 * tid] = excl;            // reuse hist as scatter cursor
    hist[2 * tid + 1] = excl + h0;
    __syncthreads();
    // scatter into LDS (bucket-ordered)
    for (int i = e0 + tid; i < e1; i += 256) {
        int s = src[i], d = dst[i];
        int b = d >> 8;
        int pos = atomicAdd(&hist[b], 1);
        stage[pos] = ((unsigned)s << 8) | (unsigned)(d & 255);
        sbkt[pos] = (unsigned short)b;
    }
    __syncthreads();
    // coalesced flush: consecutive i -> consecutive addresses within runs
    for (int i = tid; i < cnt; i += 256) {
        int b = sbkt[i];
        rec[(size_t)b * BUCK_CAP + gbase[b] + (i - lbase[b])] = stage[i];
    }
}

// Pass B (fused scanb+bhist+bscat): recompute bucket prefix from gcur, then
// per-bucket node histogram -> dis + row_ptr, LDS scan, LDS-ordered scatter,
// coalesced ssrc flush.
__global__ __launch_bounds__(256) void k_bscat(const int* __restrict__ gcur,
                                               const unsigned* __restrict__ rec,
                                               float* __restrict__ dis,
                                               int* __restrict__ row_ptr,
                                               int* __restrict__ ssrc,
                                               int n, int NB, int E) {
    __shared__ int h[256];
    __shared__ int cur[256];
    __shared__ int lb[512];
    __shared__ int stmp[256];
    __shared__ int stage[BUCK_CAP];  // 24 KB
    const int b = blockIdx.x, tid = threadIdx.x;
    // bucket prefix: exclusive scan of gcur[0..NB-1] (each block recomputes)
    int g0 = (2 * tid < NB) ? gcur[2 * tid] : 0;
    int g1 = (2 * tid + 1 < NB) ? gcur[2 * tid + 1] : 0;
    int ps = g0 + g1;
    stmp[tid] = ps;
    h[tid] = 0;
    __syncthreads();
    int xx = ps;
    for (int off = 1; off < 256; off <<= 1) {
        int y = (tid >= off) ? stmp[tid - off] : 0;
        __syncthreads();
        xx += y;
        stmp[tid] = xx;
        __syncthreads();
    }
    int ex = xx - ps;
    lb[2 * tid] = ex;
    lb[2 * tid + 1] = ex + g0;
    __syncthreads();
    const int bb = lb[b];
    if (b == 0 && tid == 0) row_ptr[n] = E;

    const int cnt = gcur[b];
    const unsigned* r = rec + (size_t)b * BUCK_CAP;
    for (int i = tid; i < cnt; i += 256)
        atomicAdd(&h[r[i] & 255u], 1);
    __syncthreads();
    const int myd = h[tid];
    const int node = b * 256 + tid;
    if (node < n) dis[node] = rsqrtf((float)myd + 1.0f);  // self-loop degree
    // inclusive scan of h (in place)
    int x = myd;
    for (int off = 1; off < 256; off <<= 1) {
        int y = (tid >= off) ? h[tid - off] : 0;
        __syncthreads();
        x += y;
        h[tid] = x;
        __syncthreads();
    }
    const int excl = x - myd;
    if (node < n) row_ptr[node] = bb + excl;
    cur[tid] = excl;
    __syncthreads();
    for (int i = tid; i < cnt; i += 256) {
        unsigned v = r[i];
        int pos = atomicAdd(&cur[v & 255u], 1);
        stage[pos] = (int)(v >> 8);
    }
    __syncthreads();
    for (int i = tid; i < cnt; i += 256) ssrc[bb + i] = stage[i];
}

// MFMA GEMM: Hp[n,64] = (BN?(X)[n,K] @ W[K,64]) * dis[row], fp16 out, f32 accum.
template <int K, bool BN, bool XH>
__global__ __launch_bounds__(256) void k_gemm(const void* __restrict__ Xv,
                                              const float* __restrict__ W,
                                              const float* __restrict__ dis,
                                              const float* __restrict__ stats,
                                              const float* __restrict__ g,
                                              const float* __restrict__ be,
                                              __half* __restrict__ Hp, int n) {
    constexpr int KS = K / 32;        // mfma k-steps
    constexpr int XSTR = K + 8;       // padded LDS row stride (halves)
    __shared__ __align__(16) __half BF[KS * 4 * 64 * 8];  // B frags, lane-contig
    __shared__ __align__(16) __half XL[64 * XSTR];
    __shared__ float muS[64], wS[64], bS[64];
    const int tid = threadIdx.x;
    const int row0 = blockIdx.x * 64;

    if constexpr (BN) {
        if (tid < 64) {
            float inv_n = 1.0f / (float)n;
            float m = stats[tid] * inv_n;
            float var = stats[64 + tid] * inv_n - m * m;
            muS[tid] = m;
            wS[tid] = rsqrtf(var + 1e-5f) * g[tid];
            bS[tid] = be[tid];
        }
    }
    // Build per-lane B fragments from W (global, L2-hot)
    for (int i = tid; i < KS * 4 * 64; i += 256) {
        int l = i & 63, fs = i >> 6;
        int ks = fs >> 2, ct = fs & 3;
        int kb = ks * 32 + ((l >> 4) << 3);
        int c = (ct << 4) + (l & 15);
        H8U t;
#pragma unroll
        for (int j = 0; j < 8; ++j) t.h[j] = __float2half_rn(W[(kb + j) * 64 + c]);
        *reinterpret_cast<uint4*>(&BF[i * 8]) = t.u;
    }
    __syncthreads();  // BF + BN consts visible

    // Stage X rows -> fp16 LDS (BN+ReLU fused for layers 1/2)
    if constexpr (!XH) {
        constexpr int Q4 = K / 4;
        const float4* X4 = (const float4*)Xv;
        for (int it = 0; it < 64 * Q4 / 256; ++it) {
            int idx = it * 256 + tid;
            int row = idx / Q4, q = idx % Q4;
            int grow = row0 + row;
            float4 v = make_float4(0.f, 0.f, 0.f, 0.f);
            if (grow < n) v = X4[(size_t)grow * Q4 + q];
            *reinterpret_cast<uint2*>(&XL[row * XSTR + q * 4]) = pack4(v.x, v.y, v.z, v.w);
        }
    } else {
        constexpr int QU = K / 4;
        const uint2* Xh = (const uint2*)Xv;
        for (int it = 0; it < 64 * QU / 256; ++it) {
            int idx = it * 256 + tid;
            int row = idx / QU, q = idx % QU;
            int grow = row0 + row;
            float4 v = make_float4(0.f, 0.f, 0.f, 0.f);
            if (grow < n) {
                v = unpack4(Xh[(size_t)grow * QU + q]);
                float4 m = *reinterpret_cast<const float4*>(&muS[q * 4]);
                float4 w4 = *reinterpret_cast<const float4*>(&wS[q * 4]);
                float4 b4 = *reinterpret_cast<const float4*>(&bS[q * 4]);
                v.x = fmaxf((v.x - m.x) * w4.x + b4.x, 0.f);
                v.y = fmaxf((v.y - m.y) * w4.y + b4.y, 0.f);
                v.z = fmaxf((v.z - m.z) * w4.z + b4.z, 0.f);
                v.w = fmaxf((v.w - m.w) * w4.w + b4.w, 0.f);
            }
            *reinterpret_cast<uint2*>(&XL[row * XSTR + q * 4]) = pack4(v.x, v.y, v.z, v.w);
        }
    }
    __syncthreads();

    const int wave = tid >> 6, lane = tid & 63;
    const __half* arow = &XL[(wave * 16 + (lane & 15)) * XSTR + ((lane >> 4) << 3)];
    f16x8 a[KS];
#pragma unroll
    for (int ks = 0; ks < KS; ++ks)
        a[ks] = *reinterpret_cast<const f16x8*>(arow + ks * 32);

    f32x4 acc[4];
#pragma unroll
    for (int ct = 0; ct < 4; ++ct) acc[ct] = (f32x4){0.f, 0.f, 0.f, 0.f};
#pragma unroll
    for (int ct = 0; ct < 4; ++ct)
#pragma unroll
        for (int ks = 0; ks < KS; ++ks) {
            f16x8 b = *reinterpret_cast<const f16x8*>(&BF[((ks * 4 + ct) * 64 + lane) * 8]);
            acc[ct] = __builtin_amdgcn_mfma_f32_16x16x32_f16(a[ks], b, acc[ct], 0, 0, 0);
        }

    const int mbase = row0 + wave * 16 + ((lane >> 4) << 2);
#pragma unroll
    for (int reg = 0; reg < 4; ++reg) {
        int grow = mbase + reg;
        if (grow < n) {
            float dd = dis[grow];
#pragma unroll
            for (int ct = 0; ct < 4; ++ct)
                Hp[(size_t)grow * 64 + ct * 16 + (lane & 15)] =
                    __float2half_rn(acc[ct][reg] * dd);
        }
    }
}

// Gather: AGG[d] = dis[d] * (Hp[d] + sum_{s in N(d)} Hp[s]).
// 8 lanes/node x uint4 (16B), fp16 rows, 8-way index prefetch.
__global__ __launch_bounds__(256) void k_gather(const int* __restrict__ row_ptr,
                                                const int* __restrict__ ssrc,
                                                const float* __restrict__ dis,
                                                const uint4* __restrict__ Hp,
                                                uint4* __restrict__ AGG, int n) {
    int t = blockIdx.x * 256 + threadIdx.x;
    int d = t >> 3;
    if (d >= n) return;
    int fi = t & 7;
    int r0 = row_ptr[d], r1 = row_ptr[d + 1];
    float a[8] = {};
    upadd8(Hp[(size_t)d * 8 + fi], a);  // self-loop contribution
    int p = r0;
    for (; p + 7 < r1; p += 8) {
        int s0 = ssrc[p], s1 = ssrc[p + 1], s2 = ssrc[p + 2], s3 = ssrc[p + 3];
        int s4 = ssrc[p + 4], s5 = ssrc[p + 5], s6 = ssrc[p + 6], s7 = ssrc[p + 7];
        uint4 q0 = Hp[(size_t)s0 * 8 + fi];
        uint4 q1 = Hp[(size_t)s1 * 8 + fi];
        uint4 q2 = Hp[(size_t)s2 * 8 + fi];
        uint4 q3 = Hp[(size_t)s3 * 8 + fi];
        uint4 q4 = Hp[(size_t)s4 * 8 + fi];
        uint4 q5 = Hp[(size_t)s5 * 8 + fi];
        uint4 q6 = Hp[(size_t)s6 * 8 + fi];
        uint4 q7 = Hp[(size_t)s7 * 8 + fi];
        upadd8(q0, a); upadd8(q1, a); upadd8(q2, a); upadd8(q3, a);
        upadd8(q4, a); upadd8(q5, a); upadd8(q6, a); upadd8(q7, a);
    }
    for (; p + 3 < r1; p += 4) {
        int s0 = ssrc[p], s1 = ssrc[p + 1], s2 = ssrc[p + 2], s3 = ssrc[p + 3];
        uint4 q0 = Hp[(size_t)s0 * 8 + fi];
        uint4 q1 = Hp[(size_t)s1 * 8 + fi];
        uint4 q2 = Hp[(size_t)s2 * 8 + fi];
        uint4 q3 = Hp[(size_t)s3 * 8 + fi];
        upadd8(q0, a); upadd8(q1, a); upadd8(q2, a); upadd8(q3, a);
    }
    for (; p < r1; ++p) upadd8(Hp[(size_t)ssrc[p] * 8 + fi], a);
    float dd = dis[d];
    H8U o;
#pragma unroll
    for (int i = 0; i < 8; ++i) o.h[i] = __float2half_rn(a[i] * dd);
    AGG[(size_t)d * 8 + fi] = o.u;
}

// BN stats: per-feature sum + sumsq over N rows; uint2 (4-feat) vector loads.
__global__ __launch_bounds__(256) void k_stats(const uint2* __restrict__ A,
                                               float* __restrict__ stats, int n) {
    __shared__ float r1[16 * 64];
    __shared__ float r2[16 * 64];
    int tid = threadIdx.x;
    int fi = tid & 15, rg = tid >> 4;
    float s0 = 0, s1 = 0, s2 = 0, s3 = 0, q0 = 0, q1 = 0, q2 = 0, q3 = 0;
    for (int row = blockIdx.x * 16 + rg; row < n; row += gridDim.x * 16) {
        float4 v = unpack4(A[(size_t)row * 16 + fi]);
        s0 += v.x; q0 += v.x * v.x;
        s1 += v.y; q1 += v.y * v.y;
        s2 += v.z; q2 += v.z * v.z;
        s3 += v.w; q3 += v.w * v.w;
    }
    r1[rg * 64 + fi * 4 + 0] = s0; r2[rg * 64 + fi * 4 + 0] = q0;
    r1[rg * 64 + fi * 4 + 1] = s1; r2[rg * 64 + fi * 4 + 1] = q1;
    r1[rg * 64 + fi * 4 + 2] = s2; r2[rg * 64 + fi * 4 + 2] = q2;
    r1[rg * 64 + fi * 4 + 3] = s3; r2[rg * 64 + fi * 4 + 3] = q3;
    __syncthreads();
    if (tid < 64) {
        float a = 0;
#pragma unroll
        for (int r = 0; r < 16; ++r) a += r1[r * 64 + tid];
        atomicAdd(&stats[tid], a);
    } else if (tid < 128) {
        int f = tid - 64;
        float a = 0;
#pragma unroll
        for (int r = 0; r < 16; ++r) a += r2[r * 64 + f];
        atomicAdd(&stats[64 + f], a);
    }
}

// Head: relu(BN(X)) -> relu(@w1+b1) -> @w2+b2 -> log_softmax. One thread/row.
__global__ __launch_bounds__(256) void k_head(const uint2* __restrict__ X,
                                              const float* __restrict__ stats,
                                              const float* __restrict__ g,
                                              const float* __restrict__ be,
                                              const float* __restrict__ w1,
                                              const float* __restrict__ b1,
                                              const float* __restrict__ w2,
                                              const float* __restrict__ b2,
                                              float* __restrict__ out, int n) {
    __shared__ __align__(16) float w1s[64 * 32];
    __shared__ __align__(16) float b1s[32];
    __shared__ float w2s[64];
    __shared__ float b2s[2];
    __shared__ float muS[64], wS[64], bS[64];
    int tid = threadIdx.x;
    for (int i = tid; i < 512; i += 256)
        reinterpret_cast<float4*>(w1s)[i] = reinterpret_cast<const float4*>(w1)[i];
    if (tid < 32) b1s[tid] = b1[tid];
    if (tid >= 64 && tid < 128) w2s[tid - 64] = w2[tid - 64];
    if (tid >= 128 && tid < 130) b2s[tid - 128] = b2[tid - 128];
    if (tid < 64) {
        float inv_n = 1.0f / (float)n;
        float m = stats[tid] * inv_n;
        float var = stats[64 + tid] * inv_n - m * m;
        muS[tid] = m;
        wS[tid] = rsqrtf(var + 1e-5f) * g[tid];
        bS[tid] = be[tid];
    }
    __syncthreads();
    int row = blockIdx.x * 256 + tid;
    if (row >= n) return;

    float4 h[8];
#pragma unroll
    for (int j4 = 0; j4 < 8; ++j4) h[j4] = reinterpret_cast<float4*>(b1s)[j4];

#pragma unroll
    for (int k4 = 0; k4 < 16; ++k4) {
        float4 xv = unpack4(X[(size_t)row * 16 + k4]);
#pragma unroll
        for (int kk = 0; kk < 4; ++kk) {
            int k = k4 * 4 + kk;
            float raw = (kk == 0) ? xv.x : (kk == 1) ? xv.y : (kk == 2) ? xv.z : xv.w;
            float xk = fmaxf((raw - muS[k]) * wS[k] + bS[k], 0.f);
            const float4* wrow = reinterpret_cast<const float4*>(&w1s[k * 32]);
#pragma unroll
            for (int j4 = 0; j4 < 8; ++j4) {
                float4 wv = wrow[j4];
                h[j4].x += xk * wv.x; h[j4].y += xk * wv.y;
                h[j4].z += xk * wv.z; h[j4].w += xk * wv.w;
            }
        }
    }
    float o0 = b2s[0], o1 = b2s[1];
#pragma unroll
    for (int j4 = 0; j4 < 8; ++j4) {
        float hv[4] = {h[j4].x, h[j4].y, h[j4].z, h[j4].w};
#pragma unroll
        for (int c = 0; c < 4; ++c) {
            float hj = fmaxf(hv[c], 0.f);
            int j = j4 * 4 + c;
            o0 += hj * w2s[2 * j];
            o1 += hj * w2s[2 * j + 1];
        }
    }
    float m = fmaxf(o0, o1);
    float l = __logf(__expf(o0 - m) + __expf(o1 - m));
    reinterpret_cast<float2*>(out)[row] = make_float2(o0 - m - l, o1 - m - l);
}

extern "C" void kernel_launch(void* const* d_in, const int* in_sizes, int n_in,
                              void* d_out, int out_size, void* d_ws, size_t ws_size,
                              hipStream_t stream) {
    const float* x    = (const float*)d_in[0];
    const int*   ei   = (const int*)d_in[1];
    const float* W0   = (const float*)d_in[2];
    const float* W1   = (const float*)d_in[4];
    const float* W2   = (const float*)d_in[6];
    const float* g0   = (const float*)d_in[8];
    const float* be0  = (const float*)d_in[9];
    const float* g1   = (const float*)d_in[10];
    const float* be1  = (const float*)d_in[11];
    const float* g2   = (const float*)d_in[12];
    const float* be2  = (const float*)d_in[13];
    const float* fc1w = (const float*)d_in[14];
    const float* fc1b = (const float*)d_in[15];
    const float* fc2w = (const float*)d_in[16];
    const float* fc2b = (const float*)d_in[17];

    const int N = in_sizes[0] / 128;
    const int E = in_sizes[1] / 2;
    const int* srcp = ei;
    const int* dstp = ei + E;
    const int NB = (N + 255) >> 8;  // 256-node buckets (<=512)

    char* ws = (char*)d_ws;
    size_t off = 0;
    auto alloc = [&](size_t bytes) -> void* {
        void* p = ws + off;
        off = (off + bytes + 255) & ~(size_t)255;
        return p;
    };
    int*      gcur    = (int*)alloc(512 * 4);
    float*    stats   = (float*)alloc(3 * 128 * 4);
    float*    dis     = (float*)alloc((size_t)N * 4);
    int*      row_ptr = (int*)alloc((size_t)(N + 1) * 4);
    unsigned* rec     = (unsigned*)alloc((size_t)NB * BUCK_CAP * 4);
    int*      ssrc    = (int*)alloc((size_t)E * 4);
    __half*   B0      = (__half*)alloc((size_t)N * 64 * 2);  // Hp fp16
    __half*   B1      = (__half*)alloc((size_t)N * 64 * 2);  // AGG fp16

    // CSR build
    k_zero<<<1, 256, 0, stream>>>(gcur, stats);
    k_part<<<(E + PB_EDGES - 1) / PB_EDGES, 256, 0, stream>>>(srcp, dstp, gcur, rec, E, NB);
    k_bscat<<<NB, 256, 0, stream>>>(gcur, rec, dis, row_ptr, ssrc, N, NB, E);

    const int gemm_grid = (N + 63) / 64;
    const int gath_grid = (N * 8 + 255) / 256;

    // Layer 0 (K=128, fp32 X, no BN)
    k_gemm<128, false, false><<<gemm_grid, 256, 0, stream>>>(x, W0, dis, nullptr, nullptr, nullptr, B0, N);
    k_gather<<<gath_grid, 256, 0, stream>>>(row_ptr, ssrc, dis, (const uint4*)B0, (uint4*)B1, N);
    k_stats<<<512, 256, 0, stream>>>((const uint2*)B1, stats + 0, N);

    // Layer 1 (K=64, fp16 X, BN0 fused)
    k_gemm<64, true, true><<<gemm_grid, 256, 0, stream>>>(B1, W1, dis, stats + 0, g0, be0, B0, N);
    k_gather<<<gath_grid, 256, 0, stream>>>(row_ptr, ssrc, dis, (const uint4*)B0, (uint4*)B1, N);
    k_stats<<<512, 256, 0, stream>>>((const uint2*)B1, stats + 128, N);

    // Layer 2 (K=64, fp16 X, BN1 fused)
    k_gemm<64, true, true><<<gemm_grid, 256, 0, stream>>>(B1, W2, dis, stats + 128, g1, be1, B0, N);
    k_gather<<<gath_grid, 256, 0, stream>>>(row_ptr, ssrc, dis, (const uint4*)B0, (uint4*)B1, N);
    k_stats<<<512, 256, 0, stream>>>((const uint2*)B1, stats + 256, N);

    // Head (BN2 fused)
    k_head<<<(N + 255) / 256, 256, 0, stream>>>((const uint2*)B1, stats + 256, g2, be2,
                                                fc1w, fc1b, fc2w, fc2b,
                                                (float*)d_out, N);
}

// Round 7
// 218.880 us; speedup vs baseline: 1.1571x; 1.1571x over previous
//
#include <hip/hip_runtime.h>
#include <hip/hip_fp16.h>
#include <math.h>

// ---------------------------------------------------------------------------
// GCN: 3x (GCNConv -> BatchNorm -> ReLU) -> fc1+ReLU -> fc2 -> log_softmax
// N=100000, E=1600000, IN=128, HID=64, classes=2.
// Conv biases cancel through BN mean-subtraction -> skipped.
// GEMMs: v_mfma_f32_16x16x32_f16 (fp16 in, fp32 accum).
// CSR per call: LDS bucket-sort partition -> per-bucket hist+scan+scatter.
// Hp/AGG intermediates fp16; BN-apply+ReLU fused into next consumer.
// BN stats fused into gather epilogue (8-replica atomics, summed by consumer).
// 11 dispatches total.
// ---------------------------------------------------------------------------

#define BUCK_CAP 6144   // slots per 256-node bucket (mean 4096, +32 sigma)
#define PB_EDGES 8192   // edges per k_part block
#define GATH_BLOCKS 2048

typedef _Float16 f16x8 __attribute__((ext_vector_type(8)));
typedef float f32x4 __attribute__((ext_vector_type(4)));

union H4U { uint2 u; __half h[4]; };
union H8U { uint4 u; __half h[8]; };

__device__ inline uint2 pack4(float a, float b, float c, float d) {
    H4U t;
    t.h[0] = __float2half_rn(a); t.h[1] = __float2half_rn(b);
    t.h[2] = __float2half_rn(c); t.h[3] = __float2half_rn(d);
    return t.u;
}
__device__ inline float4 unpack4(uint2 u) {
    H4U t; t.u = u;
    return make_float4(__half2float(t.h[0]), __half2float(t.h[1]),
                       __half2float(t.h[2]), __half2float(t.h[3]));
}
__device__ inline void upadd8(uint4 u, float* a) {
    H8U t; t.u = u;
#pragma unroll
    for (int i = 0; i < 8; ++i) a[i] += __half2float(t.h[i]);
}

// Zero gcur (512 ints) + stats (3 layers x 8 replicas x 128 floats).
__global__ __launch_bounds__(256) void k_zero(int* __restrict__ gcur,
                                              float* __restrict__ stats) {
    int t = threadIdx.x;
    gcur[t] = 0; gcur[t + 256] = 0;
#pragma unroll
    for (int k = 0; k < 12; ++k) stats[k * 256 + t] = 0.f;
}

// Pass A: LDS bucket-sort partition. Block reads 8192 edges, histograms by
// bucket (dst>>8), reserves global space (1 atomic per active bucket),
// LDS-scan -> LDS-scatter (bucket-ordered), coalesced flush.
// Record = (src<<8)|(dst&255).
__global__ __launch_bounds__(256) void k_part(const int* __restrict__ src,
                                              const int* __restrict__ dst,
                                              int* __restrict__ gcur,
                                              unsigned* __restrict__ rec,
                                              int E, int NB) {
    __shared__ int hist[512];                 // counts -> cursors
    __shared__ int lbase[512];                // local exclusive prefix
    __shared__ int gbase[512];                // reserved global base
    __shared__ int stmp[256];
    __shared__ unsigned stage[PB_EDGES];      // 32 KB
    __shared__ unsigned short sbkt[PB_EDGES]; // 16 KB
    const int tid = threadIdx.x;
    const int e0 = blockIdx.x * PB_EDGES;
    const int e1 = min(e0 + PB_EDGES, E);
    const int cnt = e1 - e0;

    hist[tid] = 0; hist[tid + 256] = 0;
    __syncthreads();
    for (int i = e0 + tid; i < e1; i += 256)
        atomicAdd(&hist[dst[i] >> 8], 1);
    __syncthreads();
    for (int b = tid; b < NB; b += 256) {
        int c = hist[b];
        gbase[b] = c ? atomicAdd(&gcur[b], c) : 0;
    }
    // exclusive scan of hist[0..511]; thread t owns entries 2t, 2t+1
    int h0 = hist[2 * tid], h1 = hist[2 * tid + 1];
    int psum = h0 + h1;
    stmp[tid] = psum;
    __syncthreads();
    int x = psum;
    for (int off = 1; off < 256; off <<= 1) {
        int y = (tid >= off) ? stmp[tid - off] : 0;
        __syncthreads();
        x += y;
        stmp[tid] = x;
        __syncthreads();
    }
    int excl = x - psum;
    lbase[2 * tid] = excl;
    lbase[2 * tid + 1] = excl + h0;
    __syncthreads();
    hist[2 * tid] = excl;            // reuse hist as scatter cursor
    hist[2 * tid + 1] = excl + h0;
    __syncthreads();
    for (int i = e0 + tid; i < e1; i += 256) {
        int s = src[i], d = dst[i];
        int b = d >> 8;
        int pos = atomicAdd(&hist[b], 1);
        stage[pos] = ((unsigned)s << 8) | (unsigned)(d & 255);
        sbkt[pos] = (unsigned short)b;
    }
    __syncthreads();
    for (int i = tid; i < cnt; i += 256) {
        int b = sbkt[i];
        rec[(size_t)b * BUCK_CAP + gbase[b] + (i - lbase[b])] = stage[i];
    }
}

// Pass B (fused scanb+bhist+bscat): recompute bucket prefix from gcur, then
// per-bucket node histogram -> dis + row_ptr, LDS scan, LDS-ordered scatter,
// coalesced ssrc flush.
__global__ __launch_bounds__(256) void k_bscat(const int* __restrict__ gcur,
                                               const unsigned* __restrict__ rec,
                                               float* __restrict__ dis,
                                               int* __restrict__ row_ptr,
                                               int* __restrict__ ssrc,
                                               int n, int NB, int E) {
    __shared__ int h[256];
    __shared__ int cur[256];
    __shared__ int lb[512];
    __shared__ int stmp[256];
    __shared__ int stage[BUCK_CAP];  // 24 KB
    const int b = blockIdx.x, tid = threadIdx.x;
    int g0 = (2 * tid < NB) ? gcur[2 * tid] : 0;
    int g1 = (2 * tid + 1 < NB) ? gcur[2 * tid + 1] : 0;
    int ps = g0 + g1;
    stmp[tid] = ps;
    h[tid] = 0;
    __syncthreads();
    int xx = ps;
    for (int off = 1; off < 256; off <<= 1) {
        int y = (tid >= off) ? stmp[tid - off] : 0;
        __syncthreads();
        xx += y;
        stmp[tid] = xx;
        __syncthreads();
    }
    int ex = xx - ps;
    lb[2 * tid] = ex;
    lb[2 * tid + 1] = ex + g0;
    __syncthreads();
    const int bb = lb[b];
    if (b == 0 && tid == 0) row_ptr[n] = E;

    const int cnt = gcur[b];
    const unsigned* r = rec + (size_t)b * BUCK_CAP;
    for (int i = tid; i < cnt; i += 256)
        atomicAdd(&h[r[i] & 255u], 1);
    __syncthreads();
    const int myd = h[tid];
    const int node = b * 256 + tid;
    if (node < n) dis[node] = rsqrtf((float)myd + 1.0f);  // self-loop degree
    int x = myd;
    for (int off = 1; off < 256; off <<= 1) {
        int y = (tid >= off) ? h[tid - off] : 0;
        __syncthreads();
        x += y;
        h[tid] = x;
        __syncthreads();
    }
    const int excl = x - myd;
    if (node < n) row_ptr[node] = bb + excl;
    cur[tid] = excl;
    __syncthreads();
    for (int i = tid; i < cnt; i += 256) {
        unsigned v = r[i];
        int pos = atomicAdd(&cur[v & 255u], 1);
        stage[pos] = (int)(v >> 8);
    }
    __syncthreads();
    for (int i = tid; i < cnt; i += 256) ssrc[bb + i] = stage[i];
}

// MFMA GEMM: Hp[n,64] = (BN?(X)[n,K] @ W[K,64]) * dis[row], fp16 out, f32 accum.
// stats layout when BN: 8 replicas x (64 sum | 64 sumsq).
template <int K, bool BN, bool XH>
__global__ __launch_bounds__(256) void k_gemm(const void* __restrict__ Xv,
                                              const float* __restrict__ W,
                                              const float* __restrict__ dis,
                                              const float* __restrict__ stats,
                                              const float* __restrict__ g,
                                              const float* __restrict__ be,
                                              __half* __restrict__ Hp, int n) {
    constexpr int KS = K / 32;        // mfma k-steps
    constexpr int XSTR = K + 8;       // padded LDS row stride (halves)
    __shared__ __align__(16) __half BF[KS * 4 * 64 * 8];  // B frags, lane-contig
    __shared__ __align__(16) __half XL[64 * XSTR];
    __shared__ float muS[64], wS[64], bS[64];
    const int tid = threadIdx.x;
    const int row0 = blockIdx.x * 64;

    if constexpr (BN) {
        if (tid < 64) {
            float s1 = 0.f, s2 = 0.f;
#pragma unroll
            for (int r = 0; r < 8; ++r) {
                s1 += stats[r * 128 + tid];
                s2 += stats[r * 128 + 64 + tid];
            }
            float inv_n = 1.0f / (float)n;
            float m = s1 * inv_n;
            float var = s2 * inv_n - m * m;
            muS[tid] = m;
            wS[tid] = rsqrtf(var + 1e-5f) * g[tid];
            bS[tid] = be[tid];
        }
    }
    // Build per-lane B fragments from W (global, L2-hot)
    for (int i = tid; i < KS * 4 * 64; i += 256) {
        int l = i & 63, fs = i >> 6;
        int ks = fs >> 2, ct = fs & 3;
        int kb = ks * 32 + ((l >> 4) << 3);
        int c = (ct << 4) + (l & 15);
        H8U t;
#pragma unroll
        for (int j = 0; j < 8; ++j) t.h[j] = __float2half_rn(W[(kb + j) * 64 + c]);
        *reinterpret_cast<uint4*>(&BF[i * 8]) = t.u;
    }
    __syncthreads();  // BF + BN consts visible

    if constexpr (!XH) {
        constexpr int Q4 = K / 4;
        const float4* X4 = (const float4*)Xv;
        for (int it = 0; it < 64 * Q4 / 256; ++it) {
            int idx = it * 256 + tid;
            int row = idx / Q4, q = idx % Q4;
            int grow = row0 + row;
            float4 v = make_float4(0.f, 0.f, 0.f, 0.f);
            if (grow < n) v = X4[(size_t)grow * Q4 + q];
            *reinterpret_cast<uint2*>(&XL[row * XSTR + q * 4]) = pack4(v.x, v.y, v.z, v.w);
        }
    } else {
        constexpr int QU = K / 4;
        const uint2* Xh = (const uint2*)Xv;
        for (int it = 0; it < 64 * QU / 256; ++it) {
            int idx = it * 256 + tid;
            int row = idx / QU, q = idx % QU;
            int grow = row0 + row;
            float4 v = make_float4(0.f, 0.f, 0.f, 0.f);
            if (grow < n) {
                v = unpack4(Xh[(size_t)grow * QU + q]);
                float4 m = *reinterpret_cast<const float4*>(&muS[q * 4]);
                float4 w4 = *reinterpret_cast<const float4*>(&wS[q * 4]);
                float4 b4 = *reinterpret_cast<const float4*>(&bS[q * 4]);
                v.x = fmaxf((v.x - m.x) * w4.x + b4.x, 0.f);
                v.y = fmaxf((v.y - m.y) * w4.y + b4.y, 0.f);
                v.z = fmaxf((v.z - m.z) * w4.z + b4.z, 0.f);
                v.w = fmaxf((v.w - m.w) * w4.w + b4.w, 0.f);
            }
            *reinterpret_cast<uint2*>(&XL[row * XSTR + q * 4]) = pack4(v.x, v.y, v.z, v.w);
        }
    }
    __syncthreads();

    const int wave = tid >> 6, lane = tid & 63;
    const __half* arow = &XL[(wave * 16 + (lane & 15)) * XSTR + ((lane >> 4) << 3)];
    f16x8 a[KS];
#pragma unroll
    for (int ks = 0; ks < KS; ++ks)
        a[ks] = *reinterpret_cast<const f16x8*>(arow + ks * 32);

    f32x4 acc[4];
#pragma unroll
    for (int ct = 0; ct < 4; ++ct) acc[ct] = (f32x4){0.f, 0.f, 0.f, 0.f};
#pragma unroll
    for (int ct = 0; ct < 4; ++ct)
#pragma unroll
        for (int ks = 0; ks < KS; ++ks) {
            f16x8 b = *reinterpret_cast<const f16x8*>(&BF[((ks * 4 + ct) * 64 + lane) * 8]);
            acc[ct] = __builtin_amdgcn_mfma_f32_16x16x32_f16(a[ks], b, acc[ct], 0, 0, 0);
        }

    const int mbase = row0 + wave * 16 + ((lane >> 4) << 2);
#pragma unroll
    for (int reg = 0; reg < 4; ++reg) {
        int grow = mbase + reg;
        if (grow < n) {
            float dd = dis[grow];
#pragma unroll
            for (int ct = 0; ct < 4; ++ct)
                Hp[(size_t)grow * 64 + ct * 16 + (lane & 15)] =
                    __float2half_rn(acc[ct][reg] * dd);
        }
    }
}

// Gather + fused BN stats: AGG[d] = dis[d] * (Hp[d] + sum_{s in N(d)} Hp[s]).
// 8 lanes/node x uint4, fixed grid (grid-stride over 32-node groups).
// Epilogue: per-block LDS reduce of sum/sumsq -> atomicAdd into replica
// stats[(blockIdx&7)*128 + {f | 64+f}].
__global__ __launch_bounds__(256) void k_gather(const int* __restrict__ row_ptr,
                                                const int* __restrict__ ssrc,
                                                const float* __restrict__ dis,
                                                const uint4* __restrict__ Hp,
                                                uint4* __restrict__ AGG,
                                                float* __restrict__ stats, int n) {
    __shared__ float red[32][64];  // 8 KB, reused for sum then sumsq
    const int tid = threadIdx.x;
    const int g = tid >> 3, fi = tid & 7;
    float sacc[8] = {}, qacc[8] = {};
    for (int d = blockIdx.x * 32 + g; d < n; d += gridDim.x * 32) {
        int r0 = row_ptr[d], r1 = row_ptr[d + 1];
        float a[8] = {};
        upadd8(Hp[(size_t)d * 8 + fi], a);  // self-loop contribution
        int p = r0;
        for (; p + 7 < r1; p += 8) {
            int s0 = ssrc[p], s1 = ssrc[p + 1], s2 = ssrc[p + 2], s3 = ssrc[p + 3];
            int s4 = ssrc[p + 4], s5 = ssrc[p + 5], s6 = ssrc[p + 6], s7 = ssrc[p + 7];
            uint4 q0 = Hp[(size_t)s0 * 8 + fi];
            uint4 q1 = Hp[(size_t)s1 * 8 + fi];
            uint4 q2 = Hp[(size_t)s2 * 8 + fi];
            uint4 q3 = Hp[(size_t)s3 * 8 + fi];
            uint4 q4 = Hp[(size_t)s4 * 8 + fi];
            uint4 q5 = Hp[(size_t)s5 * 8 + fi];
            uint4 q6 = Hp[(size_t)s6 * 8 + fi];
            uint4 q7 = Hp[(size_t)s7 * 8 + fi];
            upadd8(q0, a); upadd8(q1, a); upadd8(q2, a); upadd8(q3, a);
            upadd8(q4, a); upadd8(q5, a); upadd8(q6, a); upadd8(q7, a);
        }
        for (; p + 3 < r1; p += 4) {
            int s0 = ssrc[p], s1 = ssrc[p + 1], s2 = ssrc[p + 2], s3 = ssrc[p + 3];
            uint4 q0 = Hp[(size_t)s0 * 8 + fi];
            uint4 q1 = Hp[(size_t)s1 * 8 + fi];
            uint4 q2 = Hp[(size_t)s2 * 8 + fi];
            uint4 q3 = Hp[(size_t)s3 * 8 + fi];
            upadd8(q0, a); upadd8(q1, a); upadd8(q2, a); upadd8(q3, a);
        }
        for (; p < r1; ++p) upadd8(Hp[(size_t)ssrc[p] * 8 + fi], a);
        float dd = dis[d];
        H8U o;
#pragma unroll
        for (int i = 0; i < 8; ++i) {
            float v = a[i] * dd;
            o.h[i] = __float2half_rn(v);
            sacc[i] += v;
            qacc[i] += v * v;
        }
        AGG[(size_t)d * 8 + fi] = o.u;
    }
    // block reduce -> replica atomics
#pragma unroll
    for (int j = 0; j < 8; ++j) red[g][fi * 8 + j] = sacc[j];
    __syncthreads();
    if (tid < 64) {
        float s = 0.f;
#pragma unroll
        for (int r = 0; r < 32; ++r) s += red[r][tid];
        atomicAdd(&stats[(blockIdx.x & 7) * 128 + tid], s);
    }
    __syncthreads();
#pragma unroll
    for (int j = 0; j < 8; ++j) red[g][fi * 8 + j] = qacc[j];
    __syncthreads();
    if (tid < 64) {
        float s = 0.f;
#pragma unroll
        for (int r = 0; r < 32; ++r) s += red[r][tid];
        atomicAdd(&stats[(blockIdx.x & 7) * 128 + 64 + tid], s);
    }
}

// Head: relu(BN(X)) -> relu(@w1+b1) -> @w2+b2 -> log_softmax. One thread/row.
__global__ __launch_bounds__(256) void k_head(const uint2* __restrict__ X,
                                              const float* __restrict__ stats,
                                              const float* __restrict__ g,
                                              const float* __restrict__ be,
                                              const float* __restrict__ w1,
                                              const float* __restrict__ b1,
                                              const float* __restrict__ w2,
                                              const float* __restrict__ b2,
                                              float* __restrict__ out, int n) {
    __shared__ __align__(16) float w1s[64 * 32];
    __shared__ __align__(16) float b1s[32];
    __shared__ float w2s[64];
    __shared__ float b2s[2];
    __shared__ float muS[64], wS[64], bS[64];
    int tid = threadIdx.x;
    for (int i = tid; i < 512; i += 256)
        reinterpret_cast<float4*>(w1s)[i] = reinterpret_cast<const float4*>(w1)[i];
    if (tid < 32) b1s[tid] = b1[tid];
    if (tid >= 64 && tid < 128) w2s[tid - 64] = w2[tid - 64];
    if (tid >= 128 && tid < 130) b2s[tid - 128] = b2[tid - 128];
    if (tid < 64) {
        float s1 = 0.f, s2 = 0.f;
#pragma unroll
        for (int r = 0; r < 8; ++r) {
            s1 += stats[r * 128 + tid];
            s2 += stats[r * 128 + 64 + tid];
        }
        float inv_n = 1.0f / (float)n;
        float m = s1 * inv_n;
        float var = s2 * inv_n - m * m;
        muS[tid] = m;
        wS[tid] = rsqrtf(var + 1e-5f) * g[tid];
        bS[tid] = be[tid];
    }
    __syncthreads();
    int row = blockIdx.x * 256 + tid;
    if (row >= n) return;

    float4 h[8];
#pragma unroll
    for (int j4 = 0; j4 < 8; ++j4) h[j4] = reinterpret_cast<float4*>(b1s)[j4];

#pragma unroll
    for (int k4 = 0; k4 < 16; ++k4) {
        float4 xv = unpack4(X[(size_t)row * 16 + k4]);
#pragma unroll
        for (int kk = 0; kk < 4; ++kk) {
            int k = k4 * 4 + kk;
            float raw = (kk == 0) ? xv.x : (kk == 1) ? xv.y : (kk == 2) ? xv.z : xv.w;
            float xk = fmaxf((raw - muS[k]) * wS[k] + bS[k], 0.f);
            const float4* wrow = reinterpret_cast<const float4*>(&w1s[k * 32]);
#pragma unroll
            for (int j4 = 0; j4 < 8; ++j4) {
                float4 wv = wrow[j4];
                h[j4].x += xk * wv.x; h[j4].y += xk * wv.y;
                h[j4].z += xk * wv.z; h[j4].w += xk * wv.w;
            }
        }
    }
    float o0 = b2s[0], o1 = b2s[1];
#pragma unroll
    for (int j4 = 0; j4 < 8; ++j4) {
        float hv[4] = {h[j4].x, h[j4].y, h[j4].z, h[j4].w};
#pragma unroll
        for (int c = 0; c < 4; ++c) {
            float hj = fmaxf(hv[c], 0.f);
            int j = j4 * 4 + c;
            o0 += hj * w2s[2 * j];
            o1 += hj * w2s[2 * j + 1];
        }
    }
    float m = fmaxf(o0, o1);
    float l = __logf(__expf(o0 - m) + __expf(o1 - m));
    reinterpret_cast<float2*>(out)[row] = make_float2(o0 - m - l, o1 - m - l);
}

extern "C" void kernel_launch(void* const* d_in, const int* in_sizes, int n_in,
                              void* d_out, int out_size, void* d_ws, size_t ws_size,
                              hipStream_t stream) {
    const float* x    = (const float*)d_in[0];
    const int*   ei   = (const int*)d_in[1];
    const float* W0   = (const float*)d_in[2];
    const float* W1   = (const float*)d_in[4];
    const float* W2   = (const float*)d_in[6];
    const float* g0   = (const float*)d_in[8];
    const float* be0  = (const float*)d_in[9];
    const float* g1   = (const float*)d_in[10];
    const float* be1  = (const float*)d_in[11];
    const float* g2   = (const float*)d_in[12];
    const float* be2  = (const float*)d_in[13];
    const float* fc1w = (const float*)d_in[14];
    const float* fc1b = (const float*)d_in[15];
    const float* fc2w = (const float*)d_in[16];
    const float* fc2b = (const float*)d_in[17];

    const int N = in_sizes[0] / 128;
    const int E = in_sizes[1] / 2;
    const int* srcp = ei;
    const int* dstp = ei + E;
    const int NB = (N + 255) >> 8;  // 256-node buckets (<=512)

    char* ws = (char*)d_ws;
    size_t off = 0;
    auto alloc = [&](size_t bytes) -> void* {
        void* p = ws + off;
        off = (off + bytes + 255) & ~(size_t)255;
        return p;
    };
    int*      gcur    = (int*)alloc(512 * 4);
    float*    stats   = (float*)alloc(3 * 8 * 128 * 4);  // 3 layers x 8 replicas
    float*    dis     = (float*)alloc((size_t)N * 4);
    int*      row_ptr = (int*)alloc((size_t)(N + 1) * 4);
    unsigned* rec     = (unsigned*)alloc((size_t)NB * BUCK_CAP * 4);
    int*      ssrc    = (int*)alloc((size_t)E * 4);
    __half*   B0      = (__half*)alloc((size_t)N * 64 * 2);  // Hp fp16
    __half*   B1      = (__half*)alloc((size_t)N * 64 * 2);  // AGG fp16

    // CSR build
    k_zero<<<1, 256, 0, stream>>>(gcur, stats);
    k_part<<<(E + PB_EDGES - 1) / PB_EDGES, 256, 0, stream>>>(srcp, dstp, gcur, rec, E, NB);
    k_bscat<<<NB, 256, 0, stream>>>(gcur, rec, dis, row_ptr, ssrc, N, NB, E);

    const int gemm_grid = (N + 63) / 64;

    // Layer 0 (K=128, fp32 X, no BN)
    k_gemm<128, false, false><<<gemm_grid, 256, 0, stream>>>(x, W0, dis, nullptr, nullptr, nullptr, B0, N);
    k_gather<<<GATH_BLOCKS, 256, 0, stream>>>(row_ptr, ssrc, dis, (const uint4*)B0, (uint4*)B1, stats + 0, N);

    // Layer 1 (K=64, fp16 X, BN0 fused)
    k_gemm<64, true, true><<<gemm_grid, 256, 0, stream>>>(B1, W1, dis, stats + 0, g0, be0, B0, N);
    k_gather<<<GATH_BLOCKS, 256, 0, stream>>>(row_ptr, ssrc, dis, (const uint4*)B0, (uint4*)B1, stats + 1024, N);

    // Layer 2 (K=64, fp16 X, BN1 fused)
    k_gemm<64, true, true><<<gemm_grid, 256, 0, stream>>>(B1, W2, dis, stats + 1024, g1, be1, B0, N);
    k_gather<<<GATH_BLOCKS, 256, 0, stream>>>(row_ptr, ssrc, dis, (const uint4*)B0, (uint4*)B1, stats + 2048, N);

    // Head (BN2 fused)
    k_head<<<(N + 255) / 256, 256, 0, stream>>>((const uint2*)B1, stats + 2048, g2, be2,
                                                fc1w, fc1b, fc2w, fc2b,
                                                (float*)d_out, N);
}

// Round 8
// 217.218 us; speedup vs baseline: 1.1659x; 1.0077x over previous
//
#include <hip/hip_runtime.h>
#include <hip/hip_fp16.h>
#include <math.h>

// ---------------------------------------------------------------------------
// GCN: 3x (GCNConv -> BatchNorm -> ReLU) -> fc1+ReLU -> fc2 -> log_softmax
// N=100000, E=1600000, IN=128, HID=64, classes=2.
// Conv biases cancel through BN mean-subtraction -> skipped.
// GEMMs: v_mfma_f32_16x16x32_f16 (fp16 in, fp32 accum).
// CSR per call: 2-pass bucket partition with direct reserved-run writes
// (runs are L2-resident while filled; no LDS staging), then per-bucket
// hist+scan+direct-scatter. Hp/AGG fp16; BN-apply+ReLU fused into consumer;
// BN stats fused into gather epilogue (8-replica atomics). 10 dispatches.
// ---------------------------------------------------------------------------

#define BUCK_CAP 6144   // slots per 256-node bucket (mean 4096, +32 sigma)
#define PB_EDGES 8192   // edges per k_part block (16 per thread @ 512 thr)

typedef _Float16 f16x8 __attribute__((ext_vector_type(8)));
typedef float f32x4 __attribute__((ext_vector_type(4)));

union H4U { uint2 u; __half h[4]; };
union H8U { uint4 u; __half h[8]; };

__device__ inline uint2 pack4(float a, float b, float c, float d) {
    H4U t;
    t.h[0] = __float2half_rn(a); t.h[1] = __float2half_rn(b);
    t.h[2] = __float2half_rn(c); t.h[3] = __float2half_rn(d);
    return t.u;
}
__device__ inline float4 unpack4(uint2 u) {
    H4U t; t.u = u;
    return make_float4(__half2float(t.h[0]), __half2float(t.h[1]),
                       __half2float(t.h[2]), __half2float(t.h[3]));
}
__device__ inline void upadd8(uint4 u, float* a) {
    H8U t; t.u = u;
#pragma unroll
    for (int i = 0; i < 8; ++i) a[i] += __half2float(t.h[i]);
}

// Zero gcur (512 ints) + stats (3 layers x 8 replicas x 128 floats).
__global__ __launch_bounds__(256) void k_zero(int* __restrict__ gcur,
                                              float* __restrict__ stats) {
    int t = threadIdx.x;
    gcur[t] = 0; gcur[t + 256] = 0;
#pragma unroll
    for (int k = 0; k < 12; ++k) stats[k * 256 + t] = 0.f;
}

// Pass A: 2-pass bucket partition (bucket = dst>>8). Pass 1: LDS histogram
// (dst stashed in registers). Reserve global runs (1 atomic/bucket). Pass 2:
// LDS-cursor direct write into reserved run (consecutive offs -> mostly
// line-coalesced; runs L2-resident). Record = (src<<8)|(dst&255).
__global__ __launch_bounds__(512) void k_part(const int* __restrict__ src,
                                              const int* __restrict__ dst,
                                              int* __restrict__ gcur,
                                              unsigned* __restrict__ rec,
                                              int E, int NB) {
    __shared__ int hist[512];
    __shared__ int gbase[512];
    const int tid = threadIdx.x;
    const int e0 = blockIdx.x * PB_EDGES;
    const int e1 = min(e0 + PB_EDGES, E);
    hist[tid] = 0;
    __syncthreads();
    int dloc[PB_EDGES / 512];
#pragma unroll
    for (int it = 0; it < PB_EDGES / 512; ++it) {
        int i = e0 + it * 512 + tid;
        if (i < e1) {
            int d = dst[i];
            dloc[it] = d;
            atomicAdd(&hist[d >> 8], 1);
        } else dloc[it] = -1;
    }
    __syncthreads();
    if (tid < NB) {
        int c = hist[tid];
        gbase[tid] = c ? atomicAdd(&gcur[tid], c) : 0;
    }
    __syncthreads();
    hist[tid] = 0;
    __syncthreads();
#pragma unroll
    for (int it = 0; it < PB_EDGES / 512; ++it) {
        int d = dloc[it];
        if (d >= 0) {
            int i = e0 + it * 512 + tid;
            int b = d >> 8;
            int s = src[i];
            int off = atomicAdd(&hist[b], 1);
            rec[(size_t)b * BUCK_CAP + gbase[b] + off] =
                ((unsigned)s << 8) | (unsigned)(d & 255);
        }
    }
}

// Pass B: per-bucket. Recompute bucket prefix from gcur (512-scan), node
// histogram -> dis + row_ptr, LDS scan, direct scatter into ssrc segment
// (segment ~16KB, L2-resident while filled).
__global__ __launch_bounds__(256) void k_bscat(const int* __restrict__ gcur,
                                               const unsigned* __restrict__ rec,
                                               float* __restrict__ dis,
                                               int* __restrict__ row_ptr,
                                               int* __restrict__ ssrc,
                                               int n, int NB, int E) {
    __shared__ int h[256];
    __shared__ int cur[256];
    __shared__ int lb[512];
    __shared__ int stmp[256];
    const int b = blockIdx.x, tid = threadIdx.x;
    // bucket prefix: exclusive scan of gcur[0..NB-1]
    int g0 = (2 * tid < NB) ? gcur[2 * tid] : 0;
    int g1 = (2 * tid + 1 < NB) ? gcur[2 * tid + 1] : 0;
    int ps = g0 + g1;
    stmp[tid] = ps;
    h[tid] = 0;
    __syncthreads();
    int xx = ps;
    for (int off = 1; off < 256; off <<= 1) {
        int y = (tid >= off) ? stmp[tid - off] : 0;
        __syncthreads();
        xx += y;
        stmp[tid] = xx;
        __syncthreads();
    }
    int ex = xx - ps;
    lb[2 * tid] = ex;
    lb[2 * tid + 1] = ex + g0;
    __syncthreads();
    const int bb = lb[b];
    if (b == 0 && tid == 0) row_ptr[n] = E;

    const int cnt = gcur[b];
    const unsigned* r = rec + (size_t)b * BUCK_CAP;
    for (int i = tid; i < cnt; i += 256)
        atomicAdd(&h[r[i] & 255u], 1);
    __syncthreads();
    const int myd = h[tid];
    const int node = b * 256 + tid;
    if (node < n) dis[node] = rsqrtf((float)myd + 1.0f);  // self-loop degree
    int x = myd;
    for (int off = 1; off < 256; off <<= 1) {
        int y = (tid >= off) ? h[tid - off] : 0;
        __syncthreads();
        x += y;
        h[tid] = x;
        __syncthreads();
    }
    const int excl = x - myd;
    if (node < n) row_ptr[node] = bb + excl;
    cur[tid] = bb + excl;  // global cursor
    __syncthreads();
    for (int i = tid; i < cnt; i += 256) {
        unsigned v = r[i];
        int pos = atomicAdd(&cur[v & 255u], 1);
        ssrc[pos] = (int)(v >> 8);
    }
}

// MFMA GEMM: Hp[n,64] = (BN?(X)[n,K] @ W[K,64]) * dis[row], fp16 out, f32 accum.
// stats layout when BN: 8 replicas x (64 sum | 64 sumsq).
template <int K, bool BN, bool XH>
__global__ __launch_bounds__(256) void k_gemm(const void* __restrict__ Xv,
                                              const float* __restrict__ W,
                                              const float* __restrict__ dis,
                                              const float* __restrict__ stats,
                                              const float* __restrict__ g,
                                              const float* __restrict__ be,
                                              __half* __restrict__ Hp, int n) {
    constexpr int KS = K / 32;        // mfma k-steps
    constexpr int XSTR = K + 8;       // padded LDS row stride (halves)
    __shared__ __align__(16) __half BF[KS * 4 * 64 * 8];  // B frags, lane-contig
    __shared__ __align__(16) __half XL[64 * XSTR];
    __shared__ float muS[64], wS[64], bS[64];
    const int tid = threadIdx.x;
    const int row0 = blockIdx.x * 64;

    if constexpr (BN) {
        if (tid < 64) {
            float s1 = 0.f, s2 = 0.f;
#pragma unroll
            for (int r = 0; r < 8; ++r) {
                s1 += stats[r * 128 + tid];
                s2 += stats[r * 128 + 64 + tid];
            }
            float inv_n = 1.0f / (float)n;
            float m = s1 * inv_n;
            float var = s2 * inv_n - m * m;
            muS[tid] = m;
            wS[tid] = rsqrtf(var + 1e-5f) * g[tid];
            bS[tid] = be[tid];
        }
    }
    // Build per-lane B fragments from W (global, L2-hot)
    for (int i = tid; i < KS * 4 * 64; i += 256) {
        int l = i & 63, fs = i >> 6;
        int ks = fs >> 2, ct = fs & 3;
        int kb = ks * 32 + ((l >> 4) << 3);
        int c = (ct << 4) + (l & 15);
        H8U t;
#pragma unroll
        for (int j = 0; j < 8; ++j) t.h[j] = __float2half_rn(W[(kb + j) * 64 + c]);
        *reinterpret_cast<uint4*>(&BF[i * 8]) = t.u;
    }
    __syncthreads();  // BF + BN consts visible

    if constexpr (!XH) {
        constexpr int Q4 = K / 4;
        const float4* X4 = (const float4*)Xv;
        for (int it = 0; it < 64 * Q4 / 256; ++it) {
            int idx = it * 256 + tid;
            int row = idx / Q4, q = idx % Q4;
            int grow = row0 + row;
            float4 v = make_float4(0.f, 0.f, 0.f, 0.f);
            if (grow < n) v = X4[(size_t)grow * Q4 + q];
            *reinterpret_cast<uint2*>(&XL[row * XSTR + q * 4]) = pack4(v.x, v.y, v.z, v.w);
        }
    } else {
        constexpr int QU = K / 4;
        const uint2* Xh = (const uint2*)Xv;
        for (int it = 0; it < 64 * QU / 256; ++it) {
            int idx = it * 256 + tid;
            int row = idx / QU, q = idx % QU;
            int grow = row0 + row;
            float4 v = make_float4(0.f, 0.f, 0.f, 0.f);
            if (grow < n) {
                v = unpack4(Xh[(size_t)grow * QU + q]);
                float4 m = *reinterpret_cast<const float4*>(&muS[q * 4]);
                float4 w4 = *reinterpret_cast<const float4*>(&wS[q * 4]);
                float4 b4 = *reinterpret_cast<const float4*>(&bS[q * 4]);
                v.x = fmaxf((v.x - m.x) * w4.x + b4.x, 0.f);
                v.y = fmaxf((v.y - m.y) * w4.y + b4.y, 0.f);
                v.z = fmaxf((v.z - m.z) * w4.z + b4.z, 0.f);
                v.w = fmaxf((v.w - m.w) * w4.w + b4.w, 0.f);
            }
            *reinterpret_cast<uint2*>(&XL[row * XSTR + q * 4]) = pack4(v.x, v.y, v.z, v.w);
        }
    }
    __syncthreads();

    const int wave = tid >> 6, lane = tid & 63;
    const __half* arow = &XL[(wave * 16 + (lane & 15)) * XSTR + ((lane >> 4) << 3)];
    f16x8 a[KS];
#pragma unroll
    for (int ks = 0; ks < KS; ++ks)
        a[ks] = *reinterpret_cast<const f16x8*>(arow + ks * 32);

    f32x4 acc[4];
#pragma unroll
    for (int ct = 0; ct < 4; ++ct) acc[ct] = (f32x4){0.f, 0.f, 0.f, 0.f};
#pragma unroll
    for (int ct = 0; ct < 4; ++ct)
#pragma unroll
        for (int ks = 0; ks < KS; ++ks) {
            f16x8 b = *reinterpret_cast<const f16x8*>(&BF[((ks * 4 + ct) * 64 + lane) * 8]);
            acc[ct] = __builtin_amdgcn_mfma_f32_16x16x32_f16(a[ks], b, acc[ct], 0, 0, 0);
        }

    const int mbase = row0 + wave * 16 + ((lane >> 4) << 2);
#pragma unroll
    for (int reg = 0; reg < 4; ++reg) {
        int grow = mbase + reg;
        if (grow < n) {
            float dd = dis[grow];
#pragma unroll
            for (int ct = 0; ct < 4; ++ct)
                Hp[(size_t)grow * 64 + ct * 16 + (lane & 15)] =
                    __float2half_rn(acc[ct][reg] * dd);
        }
    }
}

// Gather + fused BN stats: AGG[d] = dis[d] * (Hp[d] + sum_{s in N(d)} Hp[s]).
// 8 lanes/node x uint4, fixed grid (grid-stride over 32-node groups).
// Epilogue: per-block LDS reduce of sum/sumsq -> atomicAdd into replica
// stats[(blockIdx&7)*128 + {f | 64+f}].
__global__ __launch_bounds__(256) void k_gather(const int* __restrict__ row_ptr,
                                                const int* __restrict__ ssrc,
                                                const float* __restrict__ dis,
                                                const uint4* __restrict__ Hp,
                                                uint4* __restrict__ AGG,
                                                float* __restrict__ stats, int n) {
    __shared__ float red[32][64];  // 8 KB, reused for sum then sumsq
    const int tid = threadIdx.x;
    const int g = tid >> 3, fi = tid & 7;
    float sacc[8] = {}, qacc[8] = {};
    for (int d = blockIdx.x * 32 + g; d < n; d += gridDim.x * 32) {
        int r0 = row_ptr[d], r1 = row_ptr[d + 1];
        float a[8] = {};
        upadd8(Hp[(size_t)d * 8 + fi], a);  // self-loop contribution
        int p = r0;
        for (; p + 7 < r1; p += 8) {
            int s0 = ssrc[p], s1 = ssrc[p + 1], s2 = ssrc[p + 2], s3 = ssrc[p + 3];
            int s4 = ssrc[p + 4], s5 = ssrc[p + 5], s6 = ssrc[p + 6], s7 = ssrc[p + 7];
            uint4 q0 = Hp[(size_t)s0 * 8 + fi];
            uint4 q1 = Hp[(size_t)s1 * 8 + fi];
            uint4 q2 = Hp[(size_t)s2 * 8 + fi];
            uint4 q3 = Hp[(size_t)s3 * 8 + fi];
            uint4 q4 = Hp[(size_t)s4 * 8 + fi];
            uint4 q5 = Hp[(size_t)s5 * 8 + fi];
            uint4 q6 = Hp[(size_t)s6 * 8 + fi];
            uint4 q7 = Hp[(size_t)s7 * 8 + fi];
            upadd8(q0, a); upadd8(q1, a); upadd8(q2, a); upadd8(q3, a);
            upadd8(q4, a); upadd8(q5, a); upadd8(q6, a); upadd8(q7, a);
        }
        for (; p + 3 < r1; p += 4) {
            int s0 = ssrc[p], s1 = ssrc[p + 1], s2 = ssrc[p + 2], s3 = ssrc[p + 3];
            uint4 q0 = Hp[(size_t)s0 * 8 + fi];
            uint4 q1 = Hp[(size_t)s1 * 8 + fi];
            uint4 q2 = Hp[(size_t)s2 * 8 + fi];
            uint4 q3 = Hp[(size_t)s3 * 8 + fi];
            upadd8(q0, a); upadd8(q1, a); upadd8(q2, a); upadd8(q3, a);
        }
        for (; p < r1; ++p) upadd8(Hp[(size_t)ssrc[p] * 8 + fi], a);
        float dd = dis[d];
        H8U o;
#pragma unroll
        for (int i = 0; i < 8; ++i) {
            float v = a[i] * dd;
            o.h[i] = __float2half_rn(v);
            sacc[i] += v;
            qacc[i] += v * v;
        }
        AGG[(size_t)d * 8 + fi] = o.u;
    }
    // block reduce -> replica atomics
#pragma unroll
    for (int j = 0; j < 8; ++j) red[g][fi * 8 + j] = sacc[j];
    __syncthreads();
    if (tid < 64) {
        float s = 0.f;
#pragma unroll
        for (int r = 0; r < 32; ++r) s += red[r][tid];
        atomicAdd(&stats[(blockIdx.x & 7) * 128 + tid], s);
    }
    __syncthreads();
#pragma unroll
    for (int j = 0; j < 8; ++j) red[g][fi * 8 + j] = qacc[j];
    __syncthreads();
    if (tid < 64) {
        float s = 0.f;
#pragma unroll
        for (int r = 0; r < 32; ++r) s += red[r][tid];
        atomicAdd(&stats[(blockIdx.x & 7) * 128 + 64 + tid], s);
    }
}

// Head: relu(BN(X)) -> relu(@w1+b1) -> @w2+b2 -> log_softmax. One thread/row.
__global__ __launch_bounds__(256) void k_head(const uint2* __restrict__ X,
                                              const float* __restrict__ stats,
                                              const float* __restrict__ g,
                                              const float* __restrict__ be,
                                              const float* __restrict__ w1,
                                              const float* __restrict__ b1,
                                              const float* __restrict__ w2,
                                              const float* __restrict__ b2,
                                              float* __restrict__ out, int n) {
    __shared__ __align__(16) float w1s[64 * 32];
    __shared__ __align__(16) float b1s[32];
    __shared__ float w2s[64];
    __shared__ float b2s[2];
    __shared__ float muS[64], wS[64], bS[64];
    int tid = threadIdx.x;
    for (int i = tid; i < 512; i += 256)
        reinterpret_cast<float4*>(w1s)[i] = reinterpret_cast<const float4*>(w1)[i];
    if (tid < 32) b1s[tid] = b1[tid];
    if (tid >= 64 && tid < 128) w2s[tid - 64] = w2[tid - 64];
    if (tid >= 128 && tid < 130) b2s[tid - 128] = b2[tid - 128];
    if (tid < 64) {
        float s1 = 0.f, s2 = 0.f;
#pragma unroll
        for (int r = 0; r < 8; ++r) {
            s1 += stats[r * 128 + tid];
            s2 += stats[r * 128 + 64 + tid];
        }
        float inv_n = 1.0f / (float)n;
        float m = s1 * inv_n;
        float var = s2 * inv_n - m * m;
        muS[tid] = m;
        wS[tid] = rsqrtf(var + 1e-5f) * g[tid];
        bS[tid] = be[tid];
    }
    __syncthreads();
    int row = blockIdx.x * 256 + tid;
    if (row >= n) return;

    float4 h[8];
#pragma unroll
    for (int j4 = 0; j4 < 8; ++j4) h[j4] = reinterpret_cast<float4*>(b1s)[j4];

#pragma unroll
    for (int k4 = 0; k4 < 16; ++k4) {
        float4 xv = unpack4(X[(size_t)row * 16 + k4]);
#pragma unroll
        for (int kk = 0; kk < 4; ++kk) {
            int k = k4 * 4 + kk;
            float raw = (kk == 0) ? xv.x : (kk == 1) ? xv.y : (kk == 2) ? xv.z : xv.w;
            float xk = fmaxf((raw - muS[k]) * wS[k] + bS[k], 0.f);
            const float4* wrow = reinterpret_cast<const float4*>(&w1s[k * 32]);
#pragma unroll
            for (int j4 = 0; j4 < 8; ++j4) {
                float4 wv = wrow[j4];
                h[j4].x += xk * wv.x; h[j4].y += xk * wv.y;
                h[j4].z += xk * wv.z; h[j4].w += xk * wv.w;
            }
        }
    }
    float o0 = b2s[0], o1 = b2s[1];
#pragma unroll
    for (int j4 = 0; j4 < 8; ++j4) {
        float hv[4] = {h[j4].x, h[j4].y, h[j4].z, h[j4].w};
#pragma unroll
        for (int c = 0; c < 4; ++c) {
            float hj = fmaxf(hv[c], 0.f);
            int j = j4 * 4 + c;
            o0 += hj * w2s[2 * j];
            o1 += hj * w2s[2 * j + 1];
        }
    }
    float m = fmaxf(o0, o1);
    float l = __logf(__expf(o0 - m) + __expf(o1 - m));
    reinterpret_cast<float2*>(out)[row] = make_float2(o0 - m - l, o1 - m - l);
}

extern "C" void kernel_launch(void* const* d_in, const int* in_sizes, int n_in,
                              void* d_out, int out_size, void* d_ws, size_t ws_size,
                              hipStream_t stream) {
    const float* x    = (const float*)d_in[0];
    const int*   ei   = (const int*)d_in[1];
    const float* W0   = (const float*)d_in[2];
    const float* W1   = (const float*)d_in[4];
    const float* W2   = (const float*)d_in[6];
    const float* g0   = (const float*)d_in[8];
    const float* be0  = (const float*)d_in[9];
    const float* g1   = (const float*)d_in[10];
    const float* be1  = (const float*)d_in[11];
    const float* g2   = (const float*)d_in[12];
    const float* be2  = (const float*)d_in[13];
    const float* fc1w = (const float*)d_in[14];
    const float* fc1b = (const float*)d_in[15];
    const float* fc2w = (const float*)d_in[16];
    const float* fc2b = (const float*)d_in[17];

    const int N = in_sizes[0] / 128;
    const int E = in_sizes[1] / 2;
    const int* srcp = ei;
    const int* dstp = ei + E;
    const int NB = (N + 255) >> 8;  // 256-node buckets (<=512)

    char* ws = (char*)d_ws;
    size_t off = 0;
    auto alloc = [&](size_t bytes) -> void* {
        void* p = ws + off;
        off = (off + bytes + 255) & ~(size_t)255;
        return p;
    };
    int*      gcur    = (int*)alloc(512 * 4);
    float*    stats   = (float*)alloc(3 * 8 * 128 * 4);  // 3 layers x 8 replicas
    float*    dis     = (float*)alloc((size_t)N * 4);
    int*      row_ptr = (int*)alloc((size_t)(N + 1) * 4);
    unsigned* rec     = (unsigned*)alloc((size_t)NB * BUCK_CAP * 4);
    int*      ssrc    = (int*)alloc((size_t)E * 4);
    __half*   B0      = (__half*)alloc((size_t)N * 64 * 2);  // Hp fp16
    __half*   B1      = (__half*)alloc((size_t)N * 64 * 2);  // AGG fp16

    // CSR build
    k_zero<<<1, 256, 0, stream>>>(gcur, stats);
    k_part<<<(E + PB_EDGES - 1) / PB_EDGES, 512, 0, stream>>>(srcp, dstp, gcur, rec, E, NB);
    k_bscat<<<NB, 256, 0, stream>>>(gcur, rec, dis, row_ptr, ssrc, N, NB, E);

    const int gemm_grid = (N + 63) / 64;

    // Layer 0 (K=128, fp32 X, no BN)
    k_gemm<128, false, false><<<gemm_grid, 256, 0, stream>>>(x, W0, dis, nullptr, nullptr, nullptr, B0, N);
    k_gather<<<2048, 256, 0, stream>>>(row_ptr, ssrc, dis, (const uint4*)B0, (uint4*)B1, stats + 0, N);

    // Layer 1 (K=64, fp16 X, BN0 fused)
    k_gemm<64, true, true><<<gemm_grid, 256, 0, stream>>>(B1, W1, dis, stats + 0, g0, be0, B0, N);
    k_gather<<<2048, 256, 0, stream>>>(row_ptr, ssrc, dis, (const uint4*)B0, (uint4*)B1, stats + 1024, N);

    // Layer 2 (K=64, fp16 X, BN1 fused)
    k_gemm<64, true, true><<<gemm_grid, 256, 0, stream>>>(B1, W2, dis, stats + 1024, g1, be1, B0, N);
    k_gather<<<2048, 256, 0, stream>>>(row_ptr, ssrc, dis, (const uint4*)B0, (uint4*)B1, stats + 2048, N);

    // Head (BN2 fused)
    k_head<<<(N + 255) / 256, 256, 0, stream>>>((const uint2*)B1, stats + 2048, g2, be2,
                                                fc1w, fc1b, fc2w, fc2b,
                                                (float*)d_out, N);
}